// Round 1
// baseline (2043.208 us; speedup 1.0000x reference)
//
#include <hip/hip_runtime.h>

#define NN 100000
#define NE 1600000
#define DD 32
#define NL 3
#define NK 3

// --- degree: deg[col[e]] += w[e] ---
__global__ void deg_kernel(const int* __restrict__ col, const float* __restrict__ w,
                           float* __restrict__ deg) {
    int e = blockIdx.x * blockDim.x + threadIdx.x;
    if (e < NE) atomicAdd(&deg[col[e]], w[e]);
}

// --- dis[n] = deg>0 ? rsqrt(deg) : 0  (in place) ---
__global__ void dis_kernel(float* __restrict__ deg) {
    int n = blockIdx.x * blockDim.x + threadIdx.x;
    if (n < NN) {
        float d = deg[n];
        deg[n] = d > 0.f ? rsqrtf(d) : 0.f;
    }
}

// --- norm[e] = dis[row]*w*dis[col] ---
__global__ void norm_kernel(const int* __restrict__ row, const int* __restrict__ col,
                            const float* __restrict__ w, const float* __restrict__ dis,
                            float* __restrict__ norm) {
    int e = blockIdx.x * blockDim.x + threadIdx.x;
    if (e < NE) norm[e] = dis[row[e]] * w[e] * dis[col[e]];
}

// --- one hop: dst[col[e], d] += norm[e] * h[row[e], d]; thread = (edge, dim) ---
__global__ void scatter_kernel(const float* __restrict__ h, const int* __restrict__ row,
                               const int* __restrict__ col, const float* __restrict__ norm,
                               float* __restrict__ dst) {
    unsigned int tid = blockIdx.x * blockDim.x + threadIdx.x;
    unsigned int e = tid >> 5;
    unsigned int d = tid & 31;
    if (e < NE) {
        float v = norm[e] * h[(size_t)row[e] * DD + d];
        atomicAdd(&dst[(size_t)col[e] * DD + d], v);
    }
}

// --- acc (+)= src @ W [+ bias]; optionally dst = relu(result) ---
// block = 256 threads = 8 nodes x 32 output dims; W staged in LDS,
// x-row broadcast via __shfl within 32-lane groups.
__global__ void matmul_kernel(const float* __restrict__ src, const float* __restrict__ Wm,
                              const float* __restrict__ bias, float* __restrict__ acc,
                              float* __restrict__ dst, int init) {
    __shared__ float Ws[DD * DD];
    int tid = threadIdx.x;
    #pragma unroll
    for (int i = tid; i < DD * DD; i += 256) Ws[i] = Wm[i];
    __syncthreads();
    int nloc = tid >> 5;
    int j = tid & 31;
    int n = blockIdx.x * 8 + nloc;
    if (n >= NN) return;
    float xv = src[n * DD + j];
    float a = 0.f;
    #pragma unroll
    for (int i = 0; i < DD; ++i) {
        a += __shfl(xv, i, 32) * Ws[i * DD + j];
    }
    int idx = n * DD + j;
    float val = init ? (a + bias[j]) : (acc[idx] + a);
    if (dst) dst[idx] = fmaxf(val, 0.f);
    else     acc[idx] = val;
}

extern "C" void kernel_launch(void* const* d_in, const int* in_sizes, int n_in,
                              void* d_out, int out_size, void* d_ws, size_t ws_size,
                              hipStream_t stream) {
    const float* x  = (const float*)d_in[0];
    const int*   ei = (const int*)d_in[1];
    const float* ew = (const float*)d_in[2];
    const float* W  = (const float*)d_in[3];
    const float* b  = (const float*)d_in[4];
    float* out = (float*)d_out;

    const int* row = ei;        // edge_index[0] = source
    const int* col = ei + NE;   // edge_index[1] = target

    // workspace layout (floats): deg[N] | norm[E] | h0[N*D] | h1[N*D] | xbuf[N*D]
    float* ws   = (float*)d_ws;
    float* deg  = ws;
    float* norm = deg + NN;
    float* h0   = norm + NE;
    float* h1   = h0 + (size_t)NN * DD;
    float* xbuf = h1 + (size_t)NN * DD;
    float* accb = out;  // use d_out as the per-layer accumulator

    hipMemsetAsync(deg, 0, NN * sizeof(float), stream);
    deg_kernel<<<(NE + 255) / 256, 256, 0, stream>>>(col, ew, deg);
    dis_kernel<<<(NN + 255) / 256, 256, 0, stream>>>(deg);
    norm_kernel<<<(NE + 255) / 256, 256, 0, stream>>>(row, col, ew, deg, norm);

    const float* cur = x;
    for (int l = 0; l < NL; ++l) {
        // out = cur @ W[l,0] + b[l]
        matmul_kernel<<<NN / 8, 256, 0, stream>>>(
            cur, W + (size_t)l * (NK + 1) * DD * DD, b + (size_t)l * DD,
            accb, nullptr, 1);
        const float* hs = cur;
        float* hd = h0;
        for (int k = 1; k <= NK; ++k) {
            hipMemsetAsync(hd, 0, (size_t)NN * DD * sizeof(float), stream);
            scatter_kernel<<<((size_t)NE * DD + 255) / 256, 256, 0, stream>>>(
                hs, row, col, norm, hd);
            float* dst = (k == NK) ? ((l == NL - 1) ? out : xbuf) : nullptr;
            matmul_kernel<<<NN / 8, 256, 0, stream>>>(
                hd, W + ((size_t)l * (NK + 1) + k) * DD * DD, nullptr,
                accb, dst, 0);
            hs = hd;
            hd = (hd == h0) ? h1 : h0;
        }
        cur = xbuf;
    }
}

// Round 2
// 1128.813 us; speedup vs baseline: 1.8101x; 1.8101x over previous
//
#include <hip/hip_runtime.h>

#define NN 100000
#define NE 1600000
#define DD 32
#define NL 3
#define NK 3
#define NB ((NN + 255) / 256)   // 391 scan blocks

// --- histogram + weighted degree at target ---
__global__ void hist_deg_kernel(const int* __restrict__ col, const float* __restrict__ w,
                                int* __restrict__ cnt, float* __restrict__ deg) {
    int e = blockIdx.x * blockDim.x + threadIdx.x;
    if (e < NE) {
        int c = col[e];
        atomicAdd(&cnt[c], 1);
        atomicAdd(&deg[c], w[e]);
    }
}

// --- dis[n] = deg>0 ? rsqrt(deg) : 0  (in place) ---
__global__ void dis_kernel(float* __restrict__ deg) {
    int n = blockIdx.x * blockDim.x + threadIdx.x;
    if (n < NN) {
        float d = deg[n];
        deg[n] = d > 0.f ? rsqrtf(d) : 0.f;
    }
}

// --- per-block exclusive scan of cnt -> ptr, block totals -> bsum ---
__global__ void scan_block_kernel(const int* __restrict__ cnt, int* __restrict__ ptr,
                                  int* __restrict__ bsum) {
    __shared__ int s[256];
    int t = threadIdx.x;
    int i = blockIdx.x * 256 + t;
    int v = (i < NN) ? cnt[i] : 0;
    s[t] = v;
    __syncthreads();
    for (int off = 1; off < 256; off <<= 1) {
        int add = (t >= off) ? s[t - off] : 0;
        __syncthreads();
        s[t] += add;
        __syncthreads();
    }
    if (i < NN) ptr[i] = s[t] - v;          // exclusive within block
    if (t == 255) bsum[blockIdx.x] = s[255]; // block total
}

// --- exclusive scan of the 391 block totals (single block, 512 threads) ---
__global__ void scan_top_kernel(int* __restrict__ bsum, int* __restrict__ ptr) {
    __shared__ int s[512];
    int t = threadIdx.x;
    int v = (t < NB) ? bsum[t] : 0;
    s[t] = v;
    __syncthreads();
    for (int off = 1; off < 512; off <<= 1) {
        int add = (t >= off) ? s[t - off] : 0;
        __syncthreads();
        s[t] += add;
        __syncthreads();
    }
    if (t < NB) bsum[t] = s[t] - v;
    if (t == 0) ptr[NN] = NE;
}

// --- add block offsets ---
__global__ void scan_add_kernel(int* __restrict__ ptr, const int* __restrict__ bsum) {
    int i = blockIdx.x * 256 + threadIdx.x;
    if (i < NN) ptr[i] += bsum[i >> 8];
}

// --- fill CSR slots: for edge (r -> c), store src=r, val=dis[r]*w*dis[c] ---
__global__ void fill_kernel(const int* __restrict__ row, const int* __restrict__ col,
                            const float* __restrict__ w, const float* __restrict__ dis,
                            const int* __restrict__ ptr, int* __restrict__ cur,
                            int* __restrict__ csrc, float* __restrict__ cval) {
    int e = blockIdx.x * blockDim.x + threadIdx.x;
    if (e < NE) {
        int r = row[e], c = col[e];
        int p = atomicAdd(&cur[c], 1);
        int idx = ptr[c] + p;
        csrc[idx] = r;
        cval[idx] = dis[r] * w[e] * dis[c];
    }
}

// --- fused hop: agg[n] = sum_{e in in(n)} val*hin[src]; then
//     acc = (first ? xin@W0 + b : acc) + agg@Wk; last: write relu(acc)->nxt.
//     One 32-lane group per node; W tiles staged in LDS; shfl-broadcast matmul.
__global__ __launch_bounds__(256) void hop_kernel(
    const float* __restrict__ hin, const float* __restrict__ xin,
    float* __restrict__ hout, float* __restrict__ acc, float* __restrict__ nxt,
    const int* __restrict__ ptr, const int* __restrict__ csrc,
    const float* __restrict__ cval,
    const float* __restrict__ W0, const float* __restrict__ bias,
    const float* __restrict__ Wk, int first, int last) {
    __shared__ float Wks[DD * DD];
    __shared__ float W0s[DD * DD];
    int tid = threadIdx.x;
    for (int i = tid; i < DD * DD; i += 256) {
        Wks[i] = Wk[i];
        if (first) W0s[i] = W0[i];
    }
    __syncthreads();
    int lane = tid & 31;
    int n = blockIdx.x * 8 + (tid >> 5);
    if (n >= NN) return;
    int p0 = ptr[n], p1 = ptr[n + 1];
    float agg = 0.f;
    for (int e0 = p0; e0 < p1; e0 += 32) {
        int m = p1 - e0;
        if (m > 32) m = 32;
        int s = 0;
        float v = 0.f;
        if (lane < m) {
            s = csrc[e0 + lane];
            v = cval[e0 + lane];
        }
        for (int j = 0; j < m; ++j) {
            int ss = __shfl(s, j, 32);
            float vv = __shfl(v, j, 32);
            agg += vv * hin[ss * DD + lane];
        }
    }
    int idx = n * DD + lane;
    float o;
    if (first) {
        float xv = xin[idx];
        o = bias[lane];
        #pragma unroll
        for (int i = 0; i < DD; ++i) o += __shfl(xv, i, 32) * W0s[i * DD + lane];
    } else {
        o = acc[idx];
    }
    #pragma unroll
    for (int i = 0; i < DD; ++i) o += __shfl(agg, i, 32) * Wks[i * DD + lane];
    if (!last) {
        hout[idx] = agg;
        acc[idx] = o;
    } else {
        nxt[idx] = fmaxf(o, 0.f);
    }
}

extern "C" void kernel_launch(void* const* d_in, const int* in_sizes, int n_in,
                              void* d_out, int out_size, void* d_ws, size_t ws_size,
                              hipStream_t stream) {
    const float* x  = (const float*)d_in[0];
    const int*   ei = (const int*)d_in[1];
    const float* ew = (const float*)d_in[2];
    const float* W  = (const float*)d_in[3];
    const float* b  = (const float*)d_in[4];
    float* out = (float*)d_out;

    const int* row = ei;        // source
    const int* col = ei + NE;   // target

    // ws layout: deg/dis[N] | cnt/cur[N] | ptr[N+1] | bsum[512] | csrc[E] | cval[E] | buf0 | buf1
    float* ws   = (float*)d_ws;
    float* deg  = ws;
    int*   cnt  = (int*)(deg + NN);
    int*   ptr  = cnt + NN;
    int*   bsum = ptr + NN + 1;
    int*   csrc = bsum + 512;
    float* cval = (float*)(csrc + NE);
    float* buf0 = cval + NE;
    float* buf1 = buf0 + (size_t)NN * DD;

    // ---- build norm + CSR-by-target ----
    hipMemsetAsync(deg, 0, NN * sizeof(float), stream);
    hipMemsetAsync(cnt, 0, NN * sizeof(int), stream);
    hist_deg_kernel<<<(NE + 255) / 256, 256, 0, stream>>>(col, ew, cnt, deg);
    dis_kernel<<<NB, 256, 0, stream>>>(deg);
    scan_block_kernel<<<NB, 256, 0, stream>>>(cnt, ptr, bsum);
    scan_top_kernel<<<1, 512, 0, stream>>>(bsum, ptr);
    scan_add_kernel<<<NB, 256, 0, stream>>>(ptr, bsum);
    hipMemsetAsync(cnt, 0, NN * sizeof(int), stream);  // reuse as cursors
    fill_kernel<<<(NE + 255) / 256, 256, 0, stream>>>(row, col, ew, deg, ptr, cnt, csrc, cval);

    // ---- layers: buffers rotate so only 2 feature buffers are needed ----
    // l=0: k1 x->buf0, k2 buf0->buf1, k3 buf1 -> relu -> buf0
    // l=1: k1 buf0->buf1, k2 buf1->buf0, k3 buf0 -> relu -> buf1
    // l=2: k1 buf1->buf0, k2 buf0->buf1, k3 buf1 -> relu -> out
    const int grid = (NN + 7) / 8;
    const float* lin = x;       // layer input (gather src + matmul src for k=1)
    float* hA = buf0;
    float* hB = buf1;
    for (int l = 0; l < NL; ++l) {
        const float* Wl = W + (size_t)l * (NK + 1) * DD * DD;
        const float* bl = b + (size_t)l * DD;
        // k=1: first (init acc with lin@W0+b), gather lin -> hA
        hop_kernel<<<grid, 256, 0, stream>>>(lin, lin, hA, out, nullptr,
                                             ptr, csrc, cval,
                                             Wl, bl, Wl + 1 * DD * DD, 1, 0);
        // k=2: gather hA -> hB
        hop_kernel<<<grid, 256, 0, stream>>>(hA, nullptr, hB, out, nullptr,
                                             ptr, csrc, cval,
                                             nullptr, nullptr, Wl + 2 * DD * DD, 0, 0);
        // k=3: last — gather hB, relu -> nxt
        float* nxt = (l == NL - 1) ? out : hA;
        hop_kernel<<<grid, 256, 0, stream>>>(hB, nullptr, nullptr, out, nxt,
                                             ptr, csrc, cval,
                                             nullptr, nullptr, Wl + 3 * DD * DD, 0, 1);
        // rotate: next layer's input is nxt (= old hA); its scratch is old lin slot
        lin = nxt;
        float* t = hA; hA = hB; hB = t;
        if (l == 0) hB = buf0;  // after l=0, buffers are {buf1, buf0}; lin=buf0 is consumed at k=1
        // general rotation: lin points at the relu output; hA/hB swap roles each layer
    }
}

// Round 3
// 678.938 us; speedup vs baseline: 3.0094x; 1.6626x over previous
//
#include <hip/hip_runtime.h>

#define NN 100000
#define NE 1600000
#define DD 32
#define NL 3
#define NK 3
#define NB ((NN + 255) / 256)   // 391 scan blocks

// --- one packed 64-bit atomic per edge: count in bits [48..], fixed-point(2^-40)
//     weight sum in bits [0..48). Returned old value gives this edge's rank. ---
__global__ void hist_rank_kernel(const int* __restrict__ col, const float* __restrict__ w,
                                 unsigned long long* __restrict__ pk, int* __restrict__ rank) {
    int e = blockIdx.x * blockDim.x + threadIdx.x;
    if (e < NE) {
        int c = col[e];
        unsigned long long enc = (1ull << 48) |
            (unsigned long long)((double)w[e] * 1099511627776.0);  // w * 2^40
        unsigned long long old = atomicAdd(&pk[c], enc);
        rank[e] = (int)(old >> 48);
    }
}

// --- unpack: cnt[n] = count, dis[n] = deg>0 ? rsqrt(deg) : 0 ---
__global__ void unpack_kernel(const unsigned long long* __restrict__ pk,
                              int* __restrict__ cnt, float* __restrict__ dis) {
    int n = blockIdx.x * blockDim.x + threadIdx.x;
    if (n < NN) {
        unsigned long long p = pk[n];
        cnt[n] = (int)(p >> 48);
        float deg = (float)((double)(p & 0xFFFFFFFFFFFFull) * (1.0 / 1099511627776.0));
        dis[n] = deg > 0.f ? rsqrtf(deg) : 0.f;
    }
}

// --- per-block exclusive scan of cnt -> ptr, block totals -> bsum ---
__global__ void scan_block_kernel(const int* __restrict__ cnt, int* __restrict__ ptr,
                                  int* __restrict__ bsum) {
    __shared__ int s[256];
    int t = threadIdx.x;
    int i = blockIdx.x * 256 + t;
    int v = (i < NN) ? cnt[i] : 0;
    s[t] = v;
    __syncthreads();
    for (int off = 1; off < 256; off <<= 1) {
        int add = (t >= off) ? s[t - off] : 0;
        __syncthreads();
        s[t] += add;
        __syncthreads();
    }
    if (i < NN) ptr[i] = s[t] - v;
    if (t == 255) bsum[blockIdx.x] = s[255];
}

__global__ void scan_top_kernel(int* __restrict__ bsum, int* __restrict__ ptr) {
    __shared__ int s[512];
    int t = threadIdx.x;
    int v = (t < NB) ? bsum[t] : 0;
    s[t] = v;
    __syncthreads();
    for (int off = 1; off < 512; off <<= 1) {
        int add = (t >= off) ? s[t - off] : 0;
        __syncthreads();
        s[t] += add;
        __syncthreads();
    }
    if (t < NB) bsum[t] = s[t] - v;
    if (t == 0) ptr[NN] = NE;
}

__global__ void scan_add_kernel(int* __restrict__ ptr, const int* __restrict__ bsum) {
    int i = blockIdx.x * 256 + threadIdx.x;
    if (i < NN) ptr[i] += bsum[i >> 8];
}

// --- fill CSR (no atomics): slot = ptr[col] + rank; epair[slot] = (src, norm) ---
__global__ void fill_kernel(const int* __restrict__ row, const int* __restrict__ col,
                            const float* __restrict__ w, const int* __restrict__ rank,
                            const float* __restrict__ dis, const int* __restrict__ ptr,
                            int2* __restrict__ epair) {
    int e = blockIdx.x * blockDim.x + threadIdx.x;
    if (e < NE) {
        int r = row[e], c = col[e];
        int slot = ptr[c] + rank[e];
        float nv = dis[r] * w[e] * dis[c];
        epair[slot] = make_int2(r, __float_as_int(nv));
    }
}

// --- fused hop: agg[n] = sum val*hin[src]; acc = (first ? xin@W0+b : acc) + agg@Wk;
//     last: nxt = relu(acc). One 32-lane group per node, 4 edges in flight via
//     quarters (8 lanes x float4 per edge row). ---
__global__ __launch_bounds__(256) void hop_kernel(
    const float4* __restrict__ hin4, const float* __restrict__ xin,
    float4* __restrict__ hout4, float* __restrict__ acc, float* __restrict__ nxt,
    const int* __restrict__ ptr, const int2* __restrict__ epair,
    const float* __restrict__ W0, const float* __restrict__ bias,
    const float* __restrict__ Wk, int first, int last) {
    __shared__ float Wks[DD * DD];
    __shared__ float W0s[DD * DD];
    int tid = threadIdx.x;
    for (int i = tid; i < DD * DD; i += 256) {
        Wks[i] = Wk[i];
        if (first) W0s[i] = W0[i];
    }
    __syncthreads();
    int lane = tid & 31;
    int q = lane >> 3;      // quarter 0..3 (edge stream)
    int d8 = lane & 7;      // float4 index within a 32-float row
    int n = blockIdx.x * 8 + (tid >> 5);
    if (n >= NN) return;
    int p0 = ptr[n], p1 = ptr[n + 1];
    float4 agg = make_float4(0.f, 0.f, 0.f, 0.f);
    for (int e0 = p0; e0 < p1; e0 += 32) {
        int m = p1 - e0;
        if (m > 32) m = 32;
        int s = 0;
        float v = 0.f;
        if (lane < m) {
            int2 ep = epair[e0 + lane];
            s = ep.x;
            v = __int_as_float(ep.y);
        }
        int nit = (m + 3) >> 2;
        for (int j = 0; j < nit; ++j) {
            int sl = j * 4 + q;                 // source lane for this quarter's edge
            int   ss = __shfl(s, sl, 32);       // 0 (safe) when sl >= m
            float vv = __shfl(v, sl, 32);       // 0 when sl >= m
            float4 r = hin4[(size_t)ss * 8 + d8];
            agg.x = fmaf(vv, r.x, agg.x);
            agg.y = fmaf(vv, r.y, agg.y);
            agg.z = fmaf(vv, r.z, agg.z);
            agg.w = fmaf(vv, r.w, agg.w);
        }
    }
    // reduce the 4 quarter-streams (same dims live at lanes with equal lane&7)
    agg.x += __shfl_xor(agg.x, 8, 32);  agg.y += __shfl_xor(agg.y, 8, 32);
    agg.z += __shfl_xor(agg.z, 8, 32);  agg.w += __shfl_xor(agg.w, 8, 32);
    agg.x += __shfl_xor(agg.x, 16, 32); agg.y += __shfl_xor(agg.y, 16, 32);
    agg.z += __shfl_xor(agg.z, 16, 32); agg.w += __shfl_xor(agg.w, 16, 32);

    int idx = n * DD + lane;
    float o;
    if (first) {
        float xv = xin[idx];
        o = bias[lane];
        #pragma unroll
        for (int i = 0; i < DD; ++i) o = fmaf(__shfl(xv, i, 32), W0s[i * DD + lane], o);
    } else {
        o = acc[idx];
    }
    // o += agg @ Wk ; agg element (4k+c) = component c of lane k (replicated)
    #pragma unroll
    for (int k = 0; k < 8; ++k) {
        float ax = __shfl(agg.x, k, 32);
        float ay = __shfl(agg.y, k, 32);
        float az = __shfl(agg.z, k, 32);
        float aw = __shfl(agg.w, k, 32);
        o = fmaf(ax, Wks[(4 * k + 0) * DD + lane], o);
        o = fmaf(ay, Wks[(4 * k + 1) * DD + lane], o);
        o = fmaf(az, Wks[(4 * k + 2) * DD + lane], o);
        o = fmaf(aw, Wks[(4 * k + 3) * DD + lane], o);
    }
    if (!last) {
        if (lane < 8) hout4[(size_t)n * 8 + lane] = agg;  // lanes 0..7 hold full sums
        acc[idx] = o;
    } else {
        nxt[idx] = fmaxf(o, 0.f);
    }
}

extern "C" void kernel_launch(void* const* d_in, const int* in_sizes, int n_in,
                              void* d_out, int out_size, void* d_ws, size_t ws_size,
                              hipStream_t stream) {
    const float* x  = (const float*)d_in[0];
    const int*   ei = (const int*)d_in[1];
    const float* ew = (const float*)d_in[2];
    const float* W  = (const float*)d_in[3];
    const float* b  = (const float*)d_in[4];
    float* out = (float*)d_out;

    const int* row = ei;        // source
    const int* col = ei + NE;   // target

    // ws layout (16B-aligned blocks):
    // pk[N] u64 | epair[E] int2 | buf0[N*D] | buf1[N*D] | rank[E] | cnt[N] | dis[N] | ptr[N+1] | bsum[512]
    char* base = (char*)d_ws;
    unsigned long long* pk = (unsigned long long*)base;               // 800,000 B
    int2*  epair = (int2*)(base + 800000);                            // 12.8 MB
    float* buf0  = (float*)(base + 800000 + 12800000);                // 12.8 MB
    float* buf1  = buf0 + (size_t)NN * DD;                            // 12.8 MB
    int*   rank  = (int*)(buf1 + (size_t)NN * DD);                    // 6.4 MB
    int*   cnt   = rank + NE;
    float* dis   = (float*)(cnt + NN);
    int*   ptr   = (int*)(dis + NN);
    int*   bsum  = ptr + NN + 1;

    // ---- build CSR-by-target + norms ----
    hipMemsetAsync(pk, 0, NN * sizeof(unsigned long long), stream);
    hist_rank_kernel<<<(NE + 255) / 256, 256, 0, stream>>>(col, ew, pk, rank);
    unpack_kernel<<<NB, 256, 0, stream>>>(pk, cnt, dis);
    scan_block_kernel<<<NB, 256, 0, stream>>>(cnt, ptr, bsum);
    scan_top_kernel<<<1, 512, 0, stream>>>(bsum, ptr);
    scan_add_kernel<<<NB, 256, 0, stream>>>(ptr, bsum);
    fill_kernel<<<(NE + 255) / 256, 256, 0, stream>>>(row, col, ew, rank, dis, ptr, epair);

    // ---- layers ----
    const int grid = NN / 8;
    float* bufs[2] = {buf0, buf1};
    const float* lin = x;
    for (int l = 0; l < NL; ++l) {
        const float* Wl = W + (size_t)l * (NK + 1) * DD * DD;
        const float* bl = b + (size_t)l * DD;
        float* hA = bufs[l & 1];
        float* hB = bufs[(l + 1) & 1];
        float* nxt = (l == NL - 1) ? out : hA;
        // k=1: init acc = lin@W0 + b, gather lin -> hA
        hop_kernel<<<grid, 256, 0, stream>>>((const float4*)lin, lin, (float4*)hA,
                                             out, nullptr, ptr, epair,
                                             Wl, bl, Wl + 1 * DD * DD, 1, 0);
        // k=2: gather hA -> hB
        hop_kernel<<<grid, 256, 0, stream>>>((const float4*)hA, nullptr, (float4*)hB,
                                             out, nullptr, ptr, epair,
                                             nullptr, nullptr, Wl + 2 * DD * DD, 0, 0);
        // k=3: gather hB, relu -> nxt
        hop_kernel<<<grid, 256, 0, stream>>>((const float4*)hB, nullptr, nullptr,
                                             out, nxt, ptr, epair,
                                             nullptr, nullptr, Wl + 3 * DD * DD, 0, 1);
        lin = nxt;
    }
}